// Round 5
// baseline (223.622 us; speedup 1.0000x reference)
//
#include <hip/hip_runtime.h>

#define BLK 256
#define CH 30

// All accesses at compile-time-constant offsets (register-resident cells).
// Runtime 'resp' handled via branchless scalar selects (no runtime array idx).
__device__ __forceinline__ float cell_loss(const float* __restrict__ p,
                                           const float* __restrict__ t) {
    const float conf_t = t[4];

    // target box -> xyxy (exact /14.0f to match numpy argmax decisions)
    const float tw = t[2], th = t[3];
    const float tx = t[0] / 14.0f, ty = t[1] / 14.0f;
    const float tx1 = tx - 0.5f * tw, ty1 = ty - 0.5f * th;
    const float tx2 = tx + 0.5f * tw, ty2 = ty + 0.5f * th;
    const float ta = tw * th;

    const float b0x = p[0], b0y = p[1], b0w = p[2], b0h = p[3], b0c = p[4];
    const float b1x = p[5], b1y = p[6], b1w = p[7], b1h = p[8], b1c = p[9];

    float iou0, iou1;
    {
        const float px = b0x / 14.0f, py = b0y / 14.0f;
        const float x1 = px - 0.5f * b0w, y1 = py - 0.5f * b0h;
        const float x2 = px + 0.5f * b0w, y2 = py + 0.5f * b0h;
        const float w = fmaxf(fminf(x2, tx2) - fmaxf(x1, tx1), 0.0f);
        const float h = fmaxf(fminf(y2, ty2) - fmaxf(y1, ty1), 0.0f);
        const float inter = w * h;
        iou0 = inter / (b0w * b0h + ta - inter);
    }
    {
        const float px = b1x / 14.0f, py = b1y / 14.0f;
        const float x1 = px - 0.5f * b1w, y1 = py - 0.5f * b1h;
        const float x2 = px + 0.5f * b1w, y2 = py + 0.5f * b1h;
        const float w = fmaxf(fminf(x2, tx2) - fmaxf(x1, tx1), 0.0f);
        const float h = fmaxf(fminf(y2, ty2) - fmaxf(y1, ty1), 0.0f);
        const float inter = w * h;
        iou1 = inter / (b1w * b1h + ta - inter);
    }

    const bool r1 = iou1 > iou0;              // argmax, first-max on ties
    const float max_iou = fmaxf(iou0, iou1);
    const float brx = r1 ? b1x : b0x;
    const float bry = r1 ? b1y : b0y;
    const float brw = r1 ? b1w : b0w;
    const float brh = r1 ? b1h : b0h;
    const float brc = r1 ? b1c : b0c;
    const float bnc = r1 ? b0c : b1c;

    const float coo = (conf_t > 0.0f) ? 1.0f : 0.0f;
    const float noo = (conf_t == 0.0f) ? 1.0f : 0.0f;

    const float d0 = brx - t[0];
    const float d1 = bry - t[1];
    const float d2 = sqrtf(brw) - sqrtf(t[2]);
    const float d3 = sqrtf(brh) - sqrtf(t[3]);
    const float loc = d0 * d0 + d1 * d1 + d2 * d2 + d3 * d3;

    const float dc = brc - max_iou;
    const float contain = dc * dc;
    const float ncontain = bnc * bnc;

    const float n4 = p[4] - t[4];
    const float n9 = p[9] - t[9];
    const float noobj = n4 * n4 + n9 * n9;

    float cls = 0.0f;
    #pragma unroll
    for (int c = 10; c < 30; ++c) {
        const float d = p[c] - t[c];
        cls += d * d;
    }

    return coo * (5.0f * loc + 2.0f * contain + ncontain + cls)
         + 0.5f * noo * noobj;
}

__global__ __launch_bounds__(BLK) void yolo_loss_kernel(
    const float* __restrict__ pred, const float* __restrict__ targ,
    float* __restrict__ out, int npairs, float inv_n)
{
    const int pr = blockIdx.x * BLK + threadIdx.x;
    float loss = 0.0f;
    if (pr < npairs) {
        // pair of cells = 240 B = 15 aligned float4s per tensor
        const float4* gp = (const float4*)pred + (size_t)pr * 15;
        const float4* gt = (const float4*)targ + (size_t)pr * 15;
        float4 pv[15], tv[15];
        #pragma unroll
        for (int k = 0; k < 15; ++k) pv[k] = gp[k];
        #pragma unroll
        for (int k = 0; k < 15; ++k) tv[k] = gt[k];
        const float* p = (const float*)pv;
        const float* t = (const float*)tv;
        loss = cell_loss(p, t) + cell_loss(p + CH, t + CH);
    }

    // wave shuffle-reduce (64 lanes), then block reduce, one atomic/block
    #pragma unroll
    for (int off = 32; off > 0; off >>= 1) loss += __shfl_down(loss, off);

    __shared__ float wsum[BLK / 64];
    const int wid = threadIdx.x >> 6;
    const int lane = threadIdx.x & 63;
    if (lane == 0) wsum[wid] = loss;
    __syncthreads();
    if (threadIdx.x == 0) {
        float s = 0.0f;
        #pragma unroll
        for (int w = 0; w < BLK / 64; ++w) s += wsum[w];
        atomicAdd(out, s * inv_n);
    }
}

extern "C" void kernel_launch(void* const* d_in, const int* in_sizes, int n_in,
                              void* d_out, int out_size, void* d_ws, size_t ws_size,
                              hipStream_t stream) {
    const float* pred = (const float*)d_in[0];
    const float* targ = (const float*)d_in[1];
    float* out = (float*)d_out;

    const long long total = in_sizes[0];          // 4096*14*14*30
    const int ncells = (int)(total / CH);         // 802816 (even)
    const int N = ncells / 196;                   // 4096
    const float inv_n = 1.0f / (float)N;
    const int npairs = ncells / 2;                // 401408 = 1568 * 256

    hipMemsetAsync(out, 0, sizeof(float) * out_size, stream);

    const int grid = (npairs + BLK - 1) / BLK;    // 1568
    hipLaunchKernelGGL(yolo_loss_kernel, dim3(grid), dim3(BLK), 0, stream,
                       pred, targ, out, npairs, inv_n);
}